// Round 5
// baseline (642.588 us; speedup 1.0000x reference)
//
#include <hip/hip_runtime.h>
#include <hip/hip_fp16.h>

// ---------------- CSR construction (unchanged) ----------------

__global__ void count_kernel(const int* __restrict__ dst, int* __restrict__ counts, int E) {
    int e = blockIdx.x * 256 + threadIdx.x;
    if (e < E) atomicAdd(&counts[dst[e]], 1);
}

__global__ void scan_local(const int* __restrict__ counts, int* __restrict__ rowptr,
                           int* __restrict__ bsums, float* __restrict__ dinv, int N) {
    __shared__ int sm[256];
    int t = threadIdx.x;
    int gid = blockIdx.x * 256 + t;
    int v = (gid < N) ? counts[gid] : 0;
    if (gid < N) dinv[gid] = rsqrtf((float)v + 1.0f);
    int x = v;
    sm[t] = x; __syncthreads();
    for (int off = 1; off < 256; off <<= 1) {
        int y = (t >= off) ? sm[t - off] : 0;
        __syncthreads();
        x += y; sm[t] = x; __syncthreads();
    }
    if (gid < N) rowptr[gid] = x - v;
    if (t == 255) bsums[blockIdx.x] = x;
}

__global__ void scan_bsums(int* bsums, int nb) {
    __shared__ int sm[512];
    int t = threadIdx.x;
    int v = (t < nb) ? bsums[t] : 0;
    int x = v;
    sm[t] = x; __syncthreads();
    for (int off = 1; off < 512; off <<= 1) {
        int y = (t >= off) ? sm[t - off] : 0;
        __syncthreads();
        x += y; sm[t] = x; __syncthreads();
    }
    if (t < nb) bsums[t] = x - v;
}

__global__ void scan_add(int* __restrict__ rowptr, const int* __restrict__ bsums, int N) {
    int gid = blockIdx.x * 256 + threadIdx.x;
    if (gid < N) rowptr[gid] += bsums[blockIdx.x];
}

__global__ void fill_kernel(const int* __restrict__ src, const int* __restrict__ dst,
                            const int* __restrict__ rowptr, int* __restrict__ fillc,
                            const float* __restrict__ dinv,
                            int2* __restrict__ edges, int E) {
    int e = blockIdx.x * 256 + threadIdx.x;
    if (e < E) {
        int d = dst[e];
        int s = src[e];
        int pos = rowptr[d] + atomicAdd(&fillc[d], 1);
        edges[pos] = make_int2(s, __float_as_int(dinv[s]));
    }
}

// ---------------- dense MM: out16 = X(f32) @ W (no bias) ----------------

__global__ void __launch_bounds__(128)
gemm64_kernel(const float* __restrict__ X, const float* __restrict__ W,
              __half* __restrict__ out, int N) {
    __shared__ float Wl[64 * 64];
    __shared__ float hbuf[2][256];
    int tid = threadIdx.x;
    int lane = tid & 63;
    for (int i = tid; i < 4096; i += 128) Wl[i] = W[i];
    __syncthreads();
    int wi = __builtin_amdgcn_readfirstlane(tid >> 6);
    float* hb = &hbuf[wi][0];
    int g0 = blockIdx.x * 2 + wi;
    int ng = gridDim.x * 2;
    int NG = (N + 3) >> 2;
    for (int g = g0; g < NG; g += ng) {
        int v0 = g * 4;
        float x0 = (v0 + 0 < N) ? X[(size_t)(v0 + 0) * 64 + lane] : 0.f;
        float x1 = (v0 + 1 < N) ? X[(size_t)(v0 + 1) * 64 + lane] : 0.f;
        float x2 = (v0 + 2 < N) ? X[(size_t)(v0 + 2) * 64 + lane] : 0.f;
        float x3 = (v0 + 3 < N) ? X[(size_t)(v0 + 3) * 64 + lane] : 0.f;
        *(float4*)&hb[lane * 4] = make_float4(x0, x1, x2, x3);
        float y0 = 0.f, y1 = 0.f, y2 = 0.f, y3 = 0.f;
#pragma unroll 8
        for (int k = 0; k < 64; ++k) {
            float4 hk = *(const float4*)&hb[k * 4];
            float w = Wl[k * 64 + lane];
            y0 = fmaf(hk.x, w, y0);
            y1 = fmaf(hk.y, w, y1);
            y2 = fmaf(hk.z, w, y2);
            y3 = fmaf(hk.w, w, y3);
        }
        if (v0 + 0 < N) out[(size_t)(v0 + 0) * 64 + lane] = __float2half(y0);
        if (v0 + 1 < N) out[(size_t)(v0 + 1) * 64 + lane] = __float2half(y1);
        if (v0 + 2 < N) out[(size_t)(v0 + 2) * 64 + lane] = __float2half(y2);
        if (v0 + 3 < N) out[(size_t)(v0 + 3) * 64 + lane] = __float2half(y3);
    }
}

// ---------------- feature-sliced aggregation pass ----------------
// Pass sl handles features [16*sl, 16*sl+16). Gathered working set =
// 100k rows x 32 B = 3.2 MB < 4 MiB/XCD L2 => gathers become L2 hits.
// Edges are streamed with NON-TEMPORAL loads so the 12.8 MB edge stream
// does not evict the resident slice; outputs use non-temporal stores.
// Wave layout: 16 edge-groups x 4 lanes; each lane loads 4 halves (8 B);
// one load instruction services 16 edges. Pad lanes hold (idx=0, ds=0).
// OUT gets the full elementwise epilogue: relu(dinv*(acc + dinv*self) + b).

__global__ void agg_pass_kernel(const __half* __restrict__ IN,
                                const unsigned long long* __restrict__ edges,
                                const int* __restrict__ rowptr, const int* __restrict__ counts,
                                const float* __restrict__ dinv, const float* __restrict__ bias,
                                float* __restrict__ OUT, int sl, int N) {
    int tid = threadIdx.x;
    int lane = tid & 63, wave = tid >> 6;
    int eg = lane >> 2;            // edge subgroup 0..15
    int fl = lane & 3;             // feature quad within slice
    int fo = sl * 16 + fl * 4;     // this lane's 4 features
    const __half* INo = IN + fo;
    float4 bb = *(const float4*)&bias[fo];
    int v0 = blockIdx.x * 4 + wave;
    int vstr = gridDim.x * 4;
    for (int v = v0; v < N; v += vstr) {
        int start = __builtin_amdgcn_readfirstlane(rowptr[v]);
        int cnt   = __builtin_amdgcn_readfirstlane(counts[v]);
        float dv = dinv[v];
        uint2 sr = *(const uint2*)&INo[(size_t)v * 64];   // self-loop slice (L2-hot)
        float a0 = 0.f, a1 = 0.f, a2 = 0.f, a3 = 0.f;
        for (int base = 0; base < cnt; base += 64) {
            int nb = min(64, cnt - base);
            int idx = 0; float ds = 0.f;
            if (lane < nb) {
                unsigned long long e = __builtin_nontemporal_load(&edges[start + base + lane]);
                idx = (int)(unsigned)(e & 0xffffffffull);
                ds  = __int_as_float((int)(unsigned)(e >> 32));
            }
            int steps = (nb + 15) >> 4;
            steps = (steps + 1) & ~1;      // 2 or 4 => unroll-2 below; shfl idx <= 63
            for (int t = 0; t < steps; t += 2) {
                int j0 = 16 * t + eg;
                int j1 = j0 + 16;
                int   s0 = __shfl(idx, j0); float f0 = __shfl(ds, j0);
                int   s1 = __shfl(idx, j1); float f1 = __shfl(ds, j1);
                uint2 r0 = *(const uint2*)&INo[(size_t)s0 * 64];
                uint2 r1 = *(const uint2*)&INo[(size_t)s1 * 64];
                float2 u0 = __half22float2(*(const __half2*)&r0.x);
                float2 u1 = __half22float2(*(const __half2*)&r0.y);
                float2 w0 = __half22float2(*(const __half2*)&r1.x);
                float2 w1 = __half22float2(*(const __half2*)&r1.y);
                a0 = fmaf(f0, u0.x, a0); a1 = fmaf(f0, u0.y, a1);
                a2 = fmaf(f0, u1.x, a2); a3 = fmaf(f0, u1.y, a3);
                a0 = fmaf(f1, w0.x, a0); a1 = fmaf(f1, w0.y, a1);
                a2 = fmaf(f1, w1.x, a2); a3 = fmaf(f1, w1.y, a3);
            }
        }
        // reduce across the 16 edge-groups (lane bits 2..5)
        a0 += __shfl_xor(a0, 4); a0 += __shfl_xor(a0, 8); a0 += __shfl_xor(a0, 16); a0 += __shfl_xor(a0, 32);
        a1 += __shfl_xor(a1, 4); a1 += __shfl_xor(a1, 8); a1 += __shfl_xor(a1, 16); a1 += __shfl_xor(a1, 32);
        a2 += __shfl_xor(a2, 4); a2 += __shfl_xor(a2, 8); a2 += __shfl_xor(a2, 16); a2 += __shfl_xor(a2, 32);
        a3 += __shfl_xor(a3, 4); a3 += __shfl_xor(a3, 8); a3 += __shfl_xor(a3, 16); a3 += __shfl_xor(a3, 32);
        // self-loop (once, post-reduce), outer dinv scale, bias, relu
        float2 sv0 = __half22float2(*(const __half2*)&sr.x);
        float2 sv1 = __half22float2(*(const __half2*)&sr.y);
        a0 = fmaf(dv, sv0.x, a0);
        a1 = fmaf(dv, sv0.y, a1);
        a2 = fmaf(dv, sv1.x, a2);
        a3 = fmaf(dv, sv1.y, a3);
        float o0 = fmaxf(fmaf(dv, a0, bb.x), 0.f);
        float o1 = fmaxf(fmaf(dv, a1, bb.y), 0.f);
        float o2 = fmaxf(fmaf(dv, a2, bb.z), 0.f);
        float o3 = fmaxf(fmaf(dv, a3, bb.w), 0.f);
        if (eg == 0) {
            float* po = &OUT[(size_t)v * 64 + fo];
            __builtin_nontemporal_store(o0, po + 0);
            __builtin_nontemporal_store(o1, po + 1);
            __builtin_nontemporal_store(o2, po + 2);
            __builtin_nontemporal_store(o3, po + 3);
        }
    }
}

// ---------------- MLP head: out = relu(H2 @ dW1 + db1) @ dW2 + db2 ----------------

__global__ void head_kernel(const float* __restrict__ H2,
                            const float* __restrict__ dW1, const float* __restrict__ db1,
                            const float* __restrict__ dW2, const float* __restrict__ db2,
                            float* __restrict__ out, int N) {
    __shared__ float D1[64 * 64];
    __shared__ float Wh[64 * 16];
    int tid = threadIdx.x;
    for (int i = tid; i < 4096; i += 256) D1[i] = dW1[i];
    for (int i = tid; i < 1024; i += 256) Wh[i] = dW2[i];
    __syncthreads();
    int lane = tid & 63, wave = tid >> 6;
    int c = lane & 15, part = lane >> 4;
    float bb1 = db1[lane];
    float ob  = db2[c];
    int NP = (N + 1) >> 1;
    int p0 = blockIdx.x * 4 + wave;
    int pstr = gridDim.x * 4;
    for (int p = p0; p < NP; p += pstr) {
        int vA = 2 * p, vB = 2 * p + 1;
        bool hasB = vB < N;
        float hA = H2[(size_t)vA * 64 + lane];
        float hB = hasB ? H2[(size_t)vB * 64 + lane] : 0.f;
        float aA = bb1, aB = bb1;
#pragma unroll 8
        for (int k = 0; k < 64; ++k) {
            float w = D1[k * 64 + lane];
            aA = fmaf(__shfl(hA, k), w, aA);
            aB = fmaf(__shfl(hB, k), w, aB);
        }
        aA = fmaxf(aA, 0.f); aB = fmaxf(aB, 0.f);
        float oA = 0.f, oB = 0.f;
#pragma unroll 8
        for (int kk = 0; kk < 16; ++kk) {
            float w = Wh[(part * 16 + kk) * 16 + c];
            oA = fmaf(__shfl(aA, part * 16 + kk), w, oA);
            oB = fmaf(__shfl(aB, part * 16 + kk), w, oB);
        }
        oA += __shfl_xor(oA, 16); oA += __shfl_xor(oA, 32);
        oB += __shfl_xor(oB, 16); oB += __shfl_xor(oB, 32);
        if (lane < 16) {
            out[(size_t)vA * 16 + lane] = oA + ob;
            if (hasB) out[(size_t)vB * 16 + lane] = oB + ob;
        }
    }
}

// ---------------- launch ----------------

extern "C" void kernel_launch(void* const* d_in, const int* in_sizes, int n_in,
                              void* d_out, int out_size, void* d_ws, size_t ws_size,
                              hipStream_t stream) {
    const float* x   = (const float*)d_in[0];
    const int*   ei  = (const int*)d_in[1];
    const float* W1  = (const float*)d_in[2];
    const float* b1  = (const float*)d_in[3];
    const float* W2  = (const float*)d_in[4];
    const float* b2  = (const float*)d_in[5];
    const float* dW1 = (const float*)d_in[6];
    const float* db1 = (const float*)d_in[7];
    const float* dW2 = (const float*)d_in[8];
    const float* db2 = (const float*)d_in[9];
    float* out = (float*)d_out;

    int N = in_sizes[0] / 64;
    int E = in_sizes[1] / 2;
    const int* src = ei;
    const int* dst = ei + E;

    size_t off = 0;
    auto alloc = [&](size_t bytes) {
        void* p = (char*)d_ws + off;
        off += (bytes + 511) & ~(size_t)511;
        return p;
    };
    int Npad = (N + 127) & ~127;
    int*    counts = (int*)alloc((size_t)Npad * 8);     // [counts | fillc]
    int*    fillc  = counts + Npad;
    int*    rowptr = (int*)alloc((size_t)N * 4);
    int*    bsums  = (int*)alloc(512 * 4);
    int2*   edges  = (int2*)alloc((size_t)E * 8);
    float*  dinv   = (float*)alloc((size_t)N * 4);
    __half* xw16   = (__half*)alloc((size_t)N * 64 * 2);
    __half* yw16   = (__half*)alloc((size_t)N * 64 * 2);
    float*  hbuf   = (float*)alloc((size_t)N * 64 * 4);  // h1, then reused as h2

    hipMemsetAsync(counts, 0, (size_t)Npad * 8, stream);

    int nbN = (N + 255) / 256;
    int nbE = (E + 255) / 256;

    count_kernel<<<nbE, 256, 0, stream>>>(dst, counts, E);
    scan_local<<<nbN, 256, 0, stream>>>(counts, rowptr, bsums, dinv, N);
    scan_bsums<<<1, 512, 0, stream>>>(bsums, nbN);
    scan_add<<<nbN, 256, 0, stream>>>(rowptr, bsums, N);
    fill_kernel<<<nbE, 256, 0, stream>>>(src, dst, rowptr, fillc, dinv, edges, E);

    // layer 1: xw = x @ W1 (fp16), sliced agg -> h1 = relu(agg + b1) (fp32)
    gemm64_kernel<<<4096, 128, 0, stream>>>(x, W1, xw16, N);
    for (int s = 0; s < 4; ++s)
        agg_pass_kernel<<<2048, 256, 0, stream>>>(xw16, (const unsigned long long*)edges,
                                                  rowptr, counts, dinv, b1, hbuf, s, N);
    // layer 2: y = h1 @ W2 (fp16), sliced agg -> h2 = relu(agg + b2) (fp32)
    gemm64_kernel<<<4096, 128, 0, stream>>>(hbuf, W2, yw16, N);
    for (int s = 0; s < 4; ++s)
        agg_pass_kernel<<<2048, 256, 0, stream>>>(yw16, (const unsigned long long*)edges,
                                                  rowptr, counts, dinv, b2, hbuf, s, N);
    // MLP head
    head_kernel<<<2048, 256, 0, stream>>>(hbuf, dW1, db1, dW2, db2, out, N);
}

// Round 6
// 404.970 us; speedup vs baseline: 1.5868x; 1.5868x over previous
//
#include <hip/hip_runtime.h>
#include <hip/hip_fp16.h>

typedef unsigned long long ull;

// ---------------- CSR construction (unchanged) ----------------

__global__ void count_kernel(const int* __restrict__ dst, int* __restrict__ counts, int E) {
    int e = blockIdx.x * 256 + threadIdx.x;
    if (e < E) atomicAdd(&counts[dst[e]], 1);
}

__global__ void scan_local(const int* __restrict__ counts, int* __restrict__ rowptr,
                           int* __restrict__ bsums, float* __restrict__ dinv, int N) {
    __shared__ int sm[256];
    int t = threadIdx.x;
    int gid = blockIdx.x * 256 + t;
    int v = (gid < N) ? counts[gid] : 0;
    if (gid < N) dinv[gid] = rsqrtf((float)v + 1.0f);
    int x = v;
    sm[t] = x; __syncthreads();
    for (int off = 1; off < 256; off <<= 1) {
        int y = (t >= off) ? sm[t - off] : 0;
        __syncthreads();
        x += y; sm[t] = x; __syncthreads();
    }
    if (gid < N) rowptr[gid] = x - v;
    if (t == 255) bsums[blockIdx.x] = x;
}

__global__ void scan_bsums(int* bsums, int nb) {
    __shared__ int sm[512];
    int t = threadIdx.x;
    int v = (t < nb) ? bsums[t] : 0;
    int x = v;
    sm[t] = x; __syncthreads();
    for (int off = 1; off < 512; off <<= 1) {
        int y = (t >= off) ? sm[t - off] : 0;
        __syncthreads();
        x += y; sm[t] = x; __syncthreads();
    }
    if (t < nb) bsums[t] = x - v;
}

__global__ void scan_add(int* __restrict__ rowptr, const int* __restrict__ bsums, int N) {
    int gid = blockIdx.x * 256 + threadIdx.x;
    if (gid < N) rowptr[gid] += bsums[blockIdx.x];
}

__global__ void fill_kernel(const int* __restrict__ src, const int* __restrict__ dst,
                            const int* __restrict__ rowptr, int* __restrict__ fillc,
                            const float* __restrict__ dinv,
                            int2* __restrict__ edges, int E) {
    int e = blockIdx.x * 256 + threadIdx.x;
    if (e < E) {
        int d = dst[e];
        int s = src[e];
        int pos = rowptr[d] + atomicAdd(&fillc[d], 1);
        edges[pos] = make_int2(s, __float_as_int(dinv[s]));
    }
}

// ---------------- xw = X @ W1 -> fp16 (unchanged R4) ----------------

__global__ void __launch_bounds__(128)
gemm64_kernel(const float* __restrict__ X, const float* __restrict__ W,
              __half* __restrict__ out, int N) {
    __shared__ float Wl[64 * 64];
    __shared__ float hbuf[2][256];
    int tid = threadIdx.x;
    int lane = tid & 63;
    for (int i = tid; i < 4096; i += 128) Wl[i] = W[i];
    __syncthreads();
    int wi = __builtin_amdgcn_readfirstlane(tid >> 6);
    float* hb = &hbuf[wi][0];
    int g0 = blockIdx.x * 2 + wi;
    int ng = gridDim.x * 2;
    int NG = (N + 3) >> 2;
    for (int g = g0; g < NG; g += ng) {
        int v0 = g * 4;
        float x0 = (v0 + 0 < N) ? X[(size_t)(v0 + 0) * 64 + lane] : 0.f;
        float x1 = (v0 + 1 < N) ? X[(size_t)(v0 + 1) * 64 + lane] : 0.f;
        float x2 = (v0 + 2 < N) ? X[(size_t)(v0 + 2) * 64 + lane] : 0.f;
        float x3 = (v0 + 3 < N) ? X[(size_t)(v0 + 3) * 64 + lane] : 0.f;
        *(float4*)&hb[lane * 4] = make_float4(x0, x1, x2, x3);
        float y0 = 0.f, y1 = 0.f, y2 = 0.f, y3 = 0.f;
#pragma unroll 8
        for (int k = 0; k < 64; ++k) {
            float4 hk = *(const float4*)&hb[k * 4];
            float w = Wl[k * 64 + lane];
            y0 = fmaf(hk.x, w, y0);
            y1 = fmaf(hk.y, w, y1);
            y2 = fmaf(hk.z, w, y2);
            y3 = fmaf(hk.w, w, y3);
        }
        if (v0 + 0 < N) out[(size_t)(v0 + 0) * 64 + lane] = __float2half(y0);
        if (v0 + 1 < N) out[(size_t)(v0 + 1) * 64 + lane] = __float2half(y1);
        if (v0 + 2 < N) out[(size_t)(v0 + 2) * 64 + lane] = __float2half(y2);
        if (v0 + 3 < N) out[(size_t)(v0 + 3) * 64 + lane] = __float2half(y3);
    }
}

// ---- fp16 gather helper: 4 halves (8B) scaled-accumulate into fp32 ----

__device__ __forceinline__ void acc4(float* a, uint2 raw, float f) {
    float2 v0 = __half22float2(*(const __half2*)&raw.x);
    float2 v1 = __half22float2(*(const __half2*)&raw.y);
    a[0] = fmaf(f, v0.x, a[0]);
    a[1] = fmaf(f, v0.y, a[1]);
    a[2] = fmaf(f, v1.x, a[2]);
    a[3] = fmaf(f, v1.y, a[3]);
}

// ------- layer1: FOUR nodes per wave gather + LDS-broadcast MM @W2 -------
// Gather: 4 groups x 16 lanes, fp16 uint2 loads (4 in flight per t-iter,
// 16 edges serviced per window). MM: stage h transposed into per-wave
// hb[k*4+j] (4 scalar stores/lane), then 64x (b128 broadcast + Wl b32):
// ~33 LDS-ops/node vs ~96 for the bpermute-MM (R5 proved the LDS pipe is
// the MM cost: head standalone = 113us at 250 LDS-ops/pair).

__global__ void agg_mm_kernel(const __half* __restrict__ XW, const ull* __restrict__ edges,
                              const int* __restrict__ rowptr, const int* __restrict__ counts,
                              const float* __restrict__ dinv, const float* __restrict__ b1,
                              const float* __restrict__ W2, __half* __restrict__ Y, int N) {
    __shared__ float Wl[64 * 64];
    __shared__ float hb[4][256];
    int tid = threadIdx.x;
    for (int i = tid; i < 4096; i += 256) Wl[i] = W2[i];
    __syncthreads();
    int lane = tid & 63, wave = tid >> 6;
    int g = lane >> 4;
    int cb = (lane & 15) * 4;
    const __half* Xcb = XW + cb;
    float4 bb4 = *(const float4*)&b1[cb];
    float* hbw = &hb[wave][0];
    int NQ = (N + 3) >> 2;
    for (int q = blockIdx.x * 4 + wave; q < NQ; q += gridDim.x * 4) {
        int v0 = q * 4;
        bool okB = v0 + 1 < N, okC = v0 + 2 < N, okD = v0 + 3 < N;
        int vA = v0;
        int vB = okB ? v0 + 1 : v0;
        int vC = okC ? v0 + 2 : v0;
        int vD = okD ? v0 + 3 : v0;
        int stA = __builtin_amdgcn_readfirstlane(rowptr[vA]);
        int cnA = __builtin_amdgcn_readfirstlane(counts[vA]);
        int stB = __builtin_amdgcn_readfirstlane(rowptr[vB]);
        int cnB = okB ? __builtin_amdgcn_readfirstlane(counts[vB]) : 0;
        int stC = __builtin_amdgcn_readfirstlane(rowptr[vC]);
        int cnC = okC ? __builtin_amdgcn_readfirstlane(counts[vC]) : 0;
        int stD = __builtin_amdgcn_readfirstlane(rowptr[vD]);
        int cnD = okD ? __builtin_amdgcn_readfirstlane(counts[vD]) : 0;
        float dvA = dinv[vA];
        float dvB = okB ? dinv[vB] : 0.f;
        float dvC = okC ? dinv[vC] : 0.f;
        float dvD = okD ? dinv[vD] : 0.f;
        float aA[4] = {0.f,0.f,0.f,0.f}, aB[4] = {0.f,0.f,0.f,0.f};
        float aC[4] = {0.f,0.f,0.f,0.f}, aD[4] = {0.f,0.f,0.f,0.f};
        int cntM = max(max(cnA, cnB), max(cnC, cnD));
        for (int base = 0; base < cntM; base += 64) {
            int nA = min(64, cnA - base), nB = min(64, cnB - base);
            int nC = min(64, cnC - base), nD = min(64, cnD - base);
            int iA = 0, iB = 0, iC = 0, iD = 0;
            float fA = 0.f, fB = 0.f, fC = 0.f, fD = 0.f;
            if (lane < nA) { ull e = __builtin_nontemporal_load(&edges[stA + base + lane]); iA = (int)(unsigned)e; fA = __int_as_float((int)(unsigned)(e >> 32)); }
            if (lane < nB) { ull e = __builtin_nontemporal_load(&edges[stB + base + lane]); iB = (int)(unsigned)e; fB = __int_as_float((int)(unsigned)(e >> 32)); }
            if (lane < nC) { ull e = __builtin_nontemporal_load(&edges[stC + base + lane]); iC = (int)(unsigned)e; fC = __int_as_float((int)(unsigned)(e >> 32)); }
            if (lane < nD) { ull e = __builtin_nontemporal_load(&edges[stD + base + lane]); iD = (int)(unsigned)e; fD = __int_as_float((int)(unsigned)(e >> 32)); }
            int nbM = min(64, cntM - base);
            int nt = (nbM + 3) >> 2;
            for (int t = 0; t < nt; ++t) {
                int l = 4 * t + g;
                int   sA = __shfl(iA, l); float gA = __shfl(fA, l);
                int   sB = __shfl(iB, l); float gB = __shfl(fB, l);
                int   sC = __shfl(iC, l); float gC = __shfl(fC, l);
                int   sD = __shfl(iD, l); float gD = __shfl(fD, l);
                uint2 rA = *(const uint2*)&Xcb[(size_t)sA * 64];
                uint2 rB = *(const uint2*)&Xcb[(size_t)sB * 64];
                uint2 rC = *(const uint2*)&Xcb[(size_t)sC * 64];
                uint2 rD = *(const uint2*)&Xcb[(size_t)sD * 64];
                acc4(aA, rA, gA);
                acc4(aB, rB, gB);
                acc4(aC, rC, gC);
                acc4(aD, rD, gD);
            }
        }
        // cross-group reduce (groups on lane bits 4..5)
#pragma unroll
        for (int i = 0; i < 4; ++i) {
            aA[i] += __shfl_xor(aA[i], 16); aA[i] += __shfl_xor(aA[i], 32);
            aB[i] += __shfl_xor(aB[i], 16); aB[i] += __shfl_xor(aB[i], 32);
            aC[i] += __shfl_xor(aC[i], 16); aC[i] += __shfl_xor(aC[i], 32);
            aD[i] += __shfl_xor(aD[i], 16); aD[i] += __shfl_xor(aD[i], 32);
        }
        // self-loop + outer dinv + bias + relu
        uint2 srA = *(const uint2*)&Xcb[(size_t)vA * 64];
        uint2 srB = *(const uint2*)&Xcb[(size_t)vB * 64];
        uint2 srC = *(const uint2*)&Xcb[(size_t)vC * 64];
        uint2 srD = *(const uint2*)&Xcb[(size_t)vD * 64];
        acc4(aA, srA, dvA); acc4(aB, srB, dvB);
        acc4(aC, srC, dvC); acc4(aD, srD, dvD);
        float hA[4], hB[4], hC[4], hD[4];
        const float* bbp = (const float*)&bb4;
#pragma unroll
        for (int i = 0; i < 4; ++i) {
            hA[i] = fmaxf(fmaf(dvA, aA[i], bbp[i]), 0.f);
            hB[i] = fmaxf(fmaf(dvB, aB[i], bbp[i]), 0.f);
            hC[i] = fmaxf(fmaf(dvC, aC[i], bbp[i]), 0.f);
            hD[i] = fmaxf(fmaf(dvD, aD[i], bbp[i]), 0.f);
        }
        // stage transposed: group g writes chain g (post-reduce, all groups
        // hold identical sums). Same-wave LDS write->read; compiler orders
        // via lgkmcnt (gemm64 hbuf pattern).
#pragma unroll
        for (int i = 0; i < 4; ++i) {
            float s = (g == 0) ? hA[i] : (g == 1) ? hB[i] : (g == 2) ? hC[i] : hD[i];
            hbw[(cb + i) * 4 + g] = s;
        }
        // y = h @ W2 (broadcast b128 reads, conflict-free)
        float y0 = 0.f, y1 = 0.f, y2 = 0.f, y3 = 0.f;
#pragma unroll 8
        for (int k = 0; k < 64; ++k) {
            float4 hk = *(const float4*)&hbw[k * 4];
            float w = Wl[k * 64 + lane];
            y0 = fmaf(hk.x, w, y0);
            y1 = fmaf(hk.y, w, y1);
            y2 = fmaf(hk.z, w, y2);
            y3 = fmaf(hk.w, w, y3);
        }
        Y[(size_t)(v0 + 0) * 64 + lane] = __float2half(y0);
        if (okB) Y[(size_t)(v0 + 1) * 64 + lane] = __float2half(y1);
        if (okC) Y[(size_t)(v0 + 2) * 64 + lane] = __float2half(y2);
        if (okD) Y[(size_t)(v0 + 3) * 64 + lane] = __float2half(y3);
    }
}

// ------- layer2: same 4-node gather + epilogue, then MLP head via LDS MMs -------

__global__ void agg_head_kernel(const __half* __restrict__ Yin, const ull* __restrict__ edges,
                                const int* __restrict__ rowptr, const int* __restrict__ counts,
                                const float* __restrict__ dinv, const float* __restrict__ b2,
                                const float* __restrict__ dW1, const float* __restrict__ db1,
                                const float* __restrict__ dW2, const float* __restrict__ db2,
                                float* __restrict__ out, int N) {
    __shared__ float D1[64 * 64];
    __shared__ float Wh[64 * 16];
    __shared__ float hb[4][256];
    int tid = threadIdx.x;
    for (int i = tid; i < 4096; i += 256) D1[i] = dW1[i];
    for (int i = tid; i < 1024; i += 256) Wh[i] = dW2[i];
    __syncthreads();
    int lane = tid & 63, wave = tid >> 6;
    int g = lane >> 4;
    int cb = (lane & 15) * 4;
    const __half* Ycb = Yin + cb;
    int c = lane & 15, nj = lane >> 4;
    float4 bb4 = *(const float4*)&b2[cb];
    float bb1 = db1[lane];
    float ob  = db2[c];
    float* hbw = &hb[wave][0];
    int NQ = (N + 3) >> 2;
    for (int q = blockIdx.x * 4 + wave; q < NQ; q += gridDim.x * 4) {
        int v0 = q * 4;
        bool okB = v0 + 1 < N, okC = v0 + 2 < N, okD = v0 + 3 < N;
        int vA = v0;
        int vB = okB ? v0 + 1 : v0;
        int vC = okC ? v0 + 2 : v0;
        int vD = okD ? v0 + 3 : v0;
        int stA = __builtin_amdgcn_readfirstlane(rowptr[vA]);
        int cnA = __builtin_amdgcn_readfirstlane(counts[vA]);
        int stB = __builtin_amdgcn_readfirstlane(rowptr[vB]);
        int cnB = okB ? __builtin_amdgcn_readfirstlane(counts[vB]) : 0;
        int stC = __builtin_amdgcn_readfirstlane(rowptr[vC]);
        int cnC = okC ? __builtin_amdgcn_readfirstlane(counts[vC]) : 0;
        int stD = __builtin_amdgcn_readfirstlane(rowptr[vD]);
        int cnD = okD ? __builtin_amdgcn_readfirstlane(counts[vD]) : 0;
        float dvA = dinv[vA];
        float dvB = okB ? dinv[vB] : 0.f;
        float dvC = okC ? dinv[vC] : 0.f;
        float dvD = okD ? dinv[vD] : 0.f;
        float aA[4] = {0.f,0.f,0.f,0.f}, aB[4] = {0.f,0.f,0.f,0.f};
        float aC[4] = {0.f,0.f,0.f,0.f}, aD[4] = {0.f,0.f,0.f,0.f};
        int cntM = max(max(cnA, cnB), max(cnC, cnD));
        for (int base = 0; base < cntM; base += 64) {
            int nA = min(64, cnA - base), nB = min(64, cnB - base);
            int nC = min(64, cnC - base), nD = min(64, cnD - base);
            int iA = 0, iB = 0, iC = 0, iD = 0;
            float fA = 0.f, fB = 0.f, fC = 0.f, fD = 0.f;
            if (lane < nA) { ull e = __builtin_nontemporal_load(&edges[stA + base + lane]); iA = (int)(unsigned)e; fA = __int_as_float((int)(unsigned)(e >> 32)); }
            if (lane < nB) { ull e = __builtin_nontemporal_load(&edges[stB + base + lane]); iB = (int)(unsigned)e; fB = __int_as_float((int)(unsigned)(e >> 32)); }
            if (lane < nC) { ull e = __builtin_nontemporal_load(&edges[stC + base + lane]); iC = (int)(unsigned)e; fC = __int_as_float((int)(unsigned)(e >> 32)); }
            if (lane < nD) { ull e = __builtin_nontemporal_load(&edges[stD + base + lane]); iD = (int)(unsigned)e; fD = __int_as_float((int)(unsigned)(e >> 32)); }
            int nbM = min(64, cntM - base);
            int nt = (nbM + 3) >> 2;
            for (int t = 0; t < nt; ++t) {
                int l = 4 * t + g;
                int   sA = __shfl(iA, l); float gA = __shfl(fA, l);
                int   sB = __shfl(iB, l); float gB = __shfl(fB, l);
                int   sC = __shfl(iC, l); float gC = __shfl(fC, l);
                int   sD = __shfl(iD, l); float gD = __shfl(fD, l);
                uint2 rA = *(const uint2*)&Ycb[(size_t)sA * 64];
                uint2 rB = *(const uint2*)&Ycb[(size_t)sB * 64];
                uint2 rC = *(const uint2*)&Ycb[(size_t)sC * 64];
                uint2 rD = *(const uint2*)&Ycb[(size_t)sD * 64];
                acc4(aA, rA, gA);
                acc4(aB, rB, gB);
                acc4(aC, rC, gC);
                acc4(aD, rD, gD);
            }
        }
#pragma unroll
        for (int i = 0; i < 4; ++i) {
            aA[i] += __shfl_xor(aA[i], 16); aA[i] += __shfl_xor(aA[i], 32);
            aB[i] += __shfl_xor(aB[i], 16); aB[i] += __shfl_xor(aB[i], 32);
            aC[i] += __shfl_xor(aC[i], 16); aC[i] += __shfl_xor(aC[i], 32);
            aD[i] += __shfl_xor(aD[i], 16); aD[i] += __shfl_xor(aD[i], 32);
        }
        uint2 srA = *(const uint2*)&Ycb[(size_t)vA * 64];
        uint2 srB = *(const uint2*)&Ycb[(size_t)vB * 64];
        uint2 srC = *(const uint2*)&Ycb[(size_t)vC * 64];
        uint2 srD = *(const uint2*)&Ycb[(size_t)vD * 64];
        acc4(aA, srA, dvA); acc4(aB, srB, dvB);
        acc4(aC, srC, dvC); acc4(aD, srD, dvD);
        float hA[4], hB[4], hC[4], hD[4];
        const float* bbp = (const float*)&bb4;
#pragma unroll
        for (int i = 0; i < 4; ++i) {
            hA[i] = fmaxf(fmaf(dvA, aA[i], bbp[i]), 0.f);
            hB[i] = fmaxf(fmaf(dvB, aB[i], bbp[i]), 0.f);
            hC[i] = fmaxf(fmaf(dvC, aC[i], bbp[i]), 0.f);
            hD[i] = fmaxf(fmaf(dvD, aD[i], bbp[i]), 0.f);
        }
#pragma unroll
        for (int i = 0; i < 4; ++i) {
            float s = (g == 0) ? hA[i] : (g == 1) ? hB[i] : (g == 2) ? hC[i] : hD[i];
            hbw[(cb + i) * 4 + g] = s;
        }
        // a = relu(h2 @ dW1 + db1)
        float y0 = bb1, y1 = bb1, y2 = bb1, y3 = bb1;
#pragma unroll 8
        for (int k = 0; k < 64; ++k) {
            float4 hk = *(const float4*)&hbw[k * 4];
            float w = D1[k * 64 + lane];
            y0 = fmaf(hk.x, w, y0);
            y1 = fmaf(hk.y, w, y1);
            y2 = fmaf(hk.z, w, y2);
            y3 = fmaf(hk.w, w, y3);
        }
        y0 = fmaxf(y0, 0.f); y1 = fmaxf(y1, 0.f);
        y2 = fmaxf(y2, 0.f); y3 = fmaxf(y3, 0.f);
        // drain all LDS reads before overwriting hbw with a (same wave)
        asm volatile("s_waitcnt lgkmcnt(0)" ::: "memory");
        hbw[lane * 4 + 0] = y0;
        hbw[lane * 4 + 1] = y1;
        hbw[lane * 4 + 2] = y2;
        hbw[lane * 4 + 3] = y3;
        // out = a @ dW2 + db2 : lane -> (node nj, col c)
        float o = 0.f;
#pragma unroll 8
        for (int k = 0; k < 64; ++k) {
            o = fmaf(hbw[k * 4 + nj], Wh[k * 16 + c], o);
        }
        if (v0 + nj < N) out[(size_t)(v0 + nj) * 16 + c] = o + ob;
    }
}

// ---------------- launch ----------------

extern "C" void kernel_launch(void* const* d_in, const int* in_sizes, int n_in,
                              void* d_out, int out_size, void* d_ws, size_t ws_size,
                              hipStream_t stream) {
    const float* x   = (const float*)d_in[0];
    const int*   ei  = (const int*)d_in[1];
    const float* W1  = (const float*)d_in[2];
    const float* b1  = (const float*)d_in[3];
    const float* W2  = (const float*)d_in[4];
    const float* b2  = (const float*)d_in[5];
    const float* dW1 = (const float*)d_in[6];
    const float* db1 = (const float*)d_in[7];
    const float* dW2 = (const float*)d_in[8];
    const float* db2 = (const float*)d_in[9];
    float* out = (float*)d_out;

    int N = in_sizes[0] / 64;
    int E = in_sizes[1] / 2;
    const int* src = ei;
    const int* dst = ei + E;

    size_t off = 0;
    auto alloc = [&](size_t bytes) {
        void* p = (char*)d_ws + off;
        off += (bytes + 511) & ~(size_t)511;
        return p;
    };
    int Npad = (N + 127) & ~127;
    int*    counts = (int*)alloc((size_t)Npad * 8);     // [counts | fillc]
    int*    fillc  = counts + Npad;
    int*    rowptr = (int*)alloc((size_t)N * 4);
    int*    bsums  = (int*)alloc(512 * 4);
    int2*   edges  = (int2*)alloc((size_t)E * 8);
    float*  dinv   = (float*)alloc((size_t)N * 4);
    __half* xw16   = (__half*)alloc((size_t)N * 64 * 2);
    __half* yw16   = (__half*)alloc((size_t)N * 64 * 2);

    hipMemsetAsync(counts, 0, (size_t)Npad * 8, stream);

    int nbN = (N + 255) / 256;
    int nbE = (E + 255) / 256;

    count_kernel<<<nbE, 256, 0, stream>>>(dst, counts, E);
    scan_local<<<nbN, 256, 0, stream>>>(counts, rowptr, bsums, dinv, N);
    scan_bsums<<<1, 512, 0, stream>>>(bsums, nbN);
    scan_add<<<nbN, 256, 0, stream>>>(rowptr, bsums, N);
    fill_kernel<<<nbE, 256, 0, stream>>>(src, dst, rowptr, fillc, dinv, edges, E);

    gemm64_kernel<<<4096, 128, 0, stream>>>(x, W1, xw16, N);
    agg_mm_kernel<<<2048, 256, 0, stream>>>(xw16, (const ull*)edges, rowptr, counts,
                                            dinv, b1, W2, yw16, N);
    agg_head_kernel<<<2048, 256, 0, stream>>>(yw16, (const ull*)edges, rowptr, counts,
                                              dinv, b2, dW1, db1, dW2, db2, out, N);
}